// Round 9
// baseline (290.310 us; speedup 1.0000x reference)
//
#include <hip/hip_runtime.h>

// MHA forward, bf16 MFMA everywhere. B=4 S=2048 H=1024 NH=16 D=64.
// R16: projection GEMMs moved to 256x256 tile (BK=64), per-wave 128x64
// (acc[8][4]) -> 2.67 MFMA per ds_read (was 2.0) and 2x FLOP per barrier.
// Sync skeleton deliberately conservative (R14-proven semantics): 2-buffer
// LDS (128KB), prefetch distance 1, stage-issue split 4A(ph0)+4B(ph1),
// full vmcnt(0) drain at each K-tile bottom; per-phase {reads; stage;
// barrier; lgkmcnt(0)+sched_barrier; setprio; 32 MFMA; barrier}. Phase-1
// LDS offsets = phase-0 ^ 32 (chunk bit-2 flip). R15's cross-phase read
// prefetch reverted (regressed: barriers rendezvous anyway, m196).
// proj_qkv grid 384 (32m x 12nt), proj_out 128. attn = R14 (proven:
// dbuf + __syncthreads + MFMA row-sums + z4 init + permlane P-transpose).

#define DEV __device__ __forceinline__

typedef __bf16 bf16x8 __attribute__((ext_vector_type(8)));
typedef __bf16 bf16x4 __attribute__((ext_vector_type(4)));
typedef __bf16 bf16x2 __attribute__((ext_vector_type(2)));
typedef float floatx4 __attribute__((ext_vector_type(4)));
typedef unsigned int uintx4 __attribute__((ext_vector_type(4)));

constexpr int Bdim = 4, SS = 2048, HH = 1024, NHH = 16, DD = 64;
constexpr int MM = Bdim * SS;  // 8192

DEV void async16(const void* g, void* l) {
  __builtin_amdgcn_global_load_lds(
      (const __attribute__((address_space(1))) unsigned int*)g,
      (__attribute__((address_space(3))) unsigned int*)l, 16, 0, 0);
}

DEV int swz3(int r) { return (r ^ (r >> 3)) & 7; }   // 8-chunk rows (64 cols)

// pack two f32 -> one dword of 2 bf16 (compiler emits v_cvt_pk_bf16_f32)
DEV unsigned pkbf16(float lo, float hi) {
  bf16x2 t;
  t[0] = (__bf16)lo;
  t[1] = (__bf16)hi;
  return __builtin_bit_cast(unsigned, t);
}

// v_permlane16_swap_b32: a.row{1,3} <-> b.row{0,2} (rows = 16-lane groups).
DEV void pswap16(unsigned& a, unsigned& b) {
  asm("v_permlane16_swap_b32 %0, %1" : "+v"(a), "+v"(b));
}

// ---------------- cast fp32 -> bf16 ----------------
__global__ __launch_bounds__(256) void cast_bf16_kernel(
    const float* __restrict__ x, const float* __restrict__ wq,
    const float* __restrict__ wk, const float* __restrict__ wv,
    const float* __restrict__ wo,
    __bf16* __restrict__ xb, __bf16* __restrict__ wqb, __bf16* __restrict__ wkb,
    __bf16* __restrict__ wvb, __bf16* __restrict__ wob) {
  const float* src; __bf16* dst; int n4;
  switch (blockIdx.z) {
    case 0: src = x;  dst = xb;  n4 = MM * HH / 4; break;
    case 1: src = wq; dst = wqb; n4 = HH * HH / 4; break;
    case 2: src = wk; dst = wkb; n4 = HH * HH / 4; break;
    case 3: src = wv; dst = wvb; n4 = HH * HH / 4; break;
    default: src = wo; dst = wob; n4 = HH * HH / 4; break;
  }
  int stride = gridDim.x * blockDim.x;
  for (int i = blockIdx.x * blockDim.x + threadIdx.x; i < n4; i += stride) {
    float4 v = ((const float4*)src)[i];
    bf16x4 o;
    o[0] = (__bf16)v.x; o[1] = (__bf16)v.y; o[2] = (__bf16)v.z; o[3] = (__bf16)v.w;
    ((bf16x4*)dst)[i] = o;
  }
}

// ---- 256x256 GEMM core, K=1024, 2-phase/K-tile, dbuf distance-1 ----
// 512 thr = 8 waves (2M x 4N), per-wave 128x64. LDS: A[256][64]+B[256][64]
// x2 buffers = 128 KB. Stage per K-tile: 4 A-rounds (ph0) + 4 B-rounds
// (ph1) of 8 KB. Bottom of K-tile: vmcnt(0) drain (tile kt+1 landed; all
// this wave's cb reads retired at ph1's lgkmcnt(0) before the barrier).
DEV void gemm256(const __bf16* __restrict__ Ablk, const __bf16* __restrict__ Bblk,
                 __bf16* Ab, __bf16* Bb, floatx4 acc[8][4]) {
  const int t = threadIdx.x;
  const int lane = t & 63, quad = lane >> 4, l16 = lane & 15;
  const int wid = t >> 6;
  const int wm = (wid >> 2) * 128, wn = (wid & 3) * 64;

  const int rl = t >> 3, ch = t & 7;
  const __bf16* Ag[4];
  const __bf16* Bg[4];
#pragma unroll
  for (int r = 0; r < 4; ++r) {
    Ag[r] = Ablk + (size_t)(rl + 64 * r) * HH + (ch ^ swz3(rl + 64 * r)) * 8;
    Bg[r] = Bblk + (size_t)(rl + 64 * r) * HH + (ch ^ swz3(rl + 64 * r)) * 8;
  }

  int aoff[8], boff[4];
#pragma unroll
  for (int i = 0; i < 8; ++i) {
    int ra = wm + i * 16 + l16;
    aoff[i] = ra * 64 + ((quad ^ swz3(ra)) * 8);
  }
#pragma unroll
  for (int j = 0; j < 4; ++j) {
    int rb = wn + j * 16 + l16;
    boff[j] = rb * 64 + ((quad ^ swz3(rb)) * 8);
  }

  // prologue: stage tile 0 into buffer 0; full drain (order-robust).
#pragma unroll
  for (int r = 0; r < 4; ++r) async16(Ag[r], Ab + r * 4096 + t * 8);
#pragma unroll
  for (int r = 0; r < 4; ++r) async16(Bg[r], Bb + r * 4096 + t * 8);
  asm volatile("s_waitcnt vmcnt(0)" ::: "memory");
  __builtin_amdgcn_s_barrier();

#pragma unroll 1
  for (int kt = 0; kt < 16; ++kt) {
    const int cb = kt & 1;
    const __bf16* Ac = Ab + cb * 16384;
    const __bf16* Bc = Bb + cb * 16384;
    __bf16* Asg = Ab + (cb ^ 1) * 16384;
    __bf16* Bsg = Bb + (cb ^ 1) * 16384;
    const int ks = (kt + 1) * 64;
    const bool st = kt < 15;

    bf16x8 af[8], bfr[4];
    // ---------------- phase 0 (chunks 0-3) ----------------
#pragma unroll
    for (int i = 0; i < 8; ++i) af[i] = *(const bf16x8*)&Ac[aoff[i]];
#pragma unroll
    for (int j = 0; j < 4; ++j) bfr[j] = *(const bf16x8*)&Bc[boff[j]];
    if (st) {
#pragma unroll
      for (int r = 0; r < 4; ++r) async16(Ag[r] + ks, Asg + r * 4096 + t * 8);
    }
    asm volatile("" ::: "memory");
    __builtin_amdgcn_s_barrier();
    asm volatile("s_waitcnt lgkmcnt(0)" ::: "memory");
    __builtin_amdgcn_sched_barrier(0);
    __builtin_amdgcn_s_setprio(1);
#pragma unroll
    for (int mi = 0; mi < 8; ++mi)
#pragma unroll
      for (int ni = 0; ni < 4; ++ni)
        acc[mi][ni] = __builtin_amdgcn_mfma_f32_16x16x32_bf16(af[mi], bfr[ni],
                                                              acc[mi][ni], 0, 0, 0);
    __builtin_amdgcn_s_setprio(0);
    asm volatile("" ::: "memory");
    __builtin_amdgcn_s_barrier();

    // ---------------- phase 1 (chunks 4-7: offset ^ 32) ----------------
#pragma unroll
    for (int i = 0; i < 8; ++i) af[i] = *(const bf16x8*)&Ac[aoff[i] ^ 32];
#pragma unroll
    for (int j = 0; j < 4; ++j) bfr[j] = *(const bf16x8*)&Bc[boff[j] ^ 32];
    if (st) {
#pragma unroll
      for (int r = 0; r < 4; ++r) async16(Bg[r] + ks, Bsg + r * 4096 + t * 8);
    }
    asm volatile("" ::: "memory");
    __builtin_amdgcn_s_barrier();
    asm volatile("s_waitcnt lgkmcnt(0)" ::: "memory");
    __builtin_amdgcn_sched_barrier(0);
    __builtin_amdgcn_s_setprio(1);
#pragma unroll
    for (int mi = 0; mi < 8; ++mi)
#pragma unroll
      for (int ni = 0; ni < 4; ++ni)
        acc[mi][ni] = __builtin_amdgcn_mfma_f32_16x16x32_bf16(af[mi], bfr[ni],
                                                              acc[mi][ni], 0, 0, 0);
    __builtin_amdgcn_s_setprio(0);
    // bottom: tile kt+1 fully landed (RAW); this wave's cb reads retired
    // at the lgkmcnt(0) above (WAR). Full drain -- conservative, proven.
    asm volatile("s_waitcnt vmcnt(0)" ::: "memory");
    asm volatile("" ::: "memory");
    __builtin_amdgcn_s_barrier();
  }
}

// ---------------- QKV projection: one mode per block ----------------
// grid 384 = 8 xcd x 48 slots: mp = xcd + 8*(slot&3) (0..31), nt = slot>>2
// (0..11), mode = nt>>2. x m-panels stay L2-hot per XCD across nt rounds.
__global__ __launch_bounds__(512, 2) void proj_qkv_kernel(
    const __bf16* __restrict__ xb,
    const __bf16* __restrict__ wqb, const __bf16* __restrict__ wkb,
    const __bf16* __restrict__ wvb,
    const float* __restrict__ bq, const float* __restrict__ bk,
    const float* __restrict__ bv,
    __bf16* __restrict__ Q, __bf16* __restrict__ Kc, __bf16* __restrict__ Vt) {
  __shared__ __align__(16) __bf16 Ab[2][256 * 64];
  __shared__ __align__(16) __bf16 Bb[2][256 * 64];

  const int lid = blockIdx.x;
  const int xcd = lid & 7, slot = lid >> 3;   // slot 0..47
  const int mp = xcd + 8 * (slot & 3);        // 0..31
  const int nt = slot >> 2;                   // 0..11
  const int mode = nt >> 2;
  const int n0 = (nt & 3) * 256;
  const int m0 = mp * 256;

  const __bf16* W = mode == 0 ? wqb : mode == 1 ? wkb : wvb;
  const float* bias = mode == 0 ? bq : mode == 1 ? bk : bv;

  floatx4 acc[8][4] = {};
  gemm256(xb + (size_t)m0 * HH, W + (size_t)n0 * HH, &Ab[0][0], &Bb[0][0], acc);

  const int t = threadIdx.x, lane = t & 63, quad = lane >> 4, l16 = lane & 15;
  const int wid = t >> 6, wm = (wid >> 2) * 128, wn = (wid & 3) * 64;
  const float qscale = 0.125f * 1.44269504088896f;  // 1/sqrt(D) * log2(e)

#pragma unroll
  for (int ni = 0; ni < 4; ++ni) {
    int n = n0 + wn + ni * 16 + l16;   // 0..1023 within mode
    float bval = bias[n];
    int h = n >> 6, d = n & 63;
#pragma unroll
    for (int mi = 0; mi < 8; ++mi) {
      int mbase = m0 + wm + mi * 16 + quad * 4;
      int bb = mbase >> 11, sbase = mbase & (SS - 1);
      size_t bh = (size_t)(bb * NHH + h);
      if (mode == 2) {
        bf16x4 pv;
#pragma unroll
        for (int r = 0; r < 4; ++r) pv[r] = (__bf16)(acc[mi][ni][r] + bval);
        *(bf16x4*)&Vt[(bh * DD + d) * SS + sbase] = pv;
      } else {
#pragma unroll
        for (int r = 0; r < 4; ++r) {
          float v = acc[mi][ni][r] + bval;
          if (mode == 0) Q [(bh * SS + sbase + r) * DD + d] = (__bf16)(v * qscale);
          else           Kc[(bh * SS + sbase + r) * DD + d] = (__bf16)v;
        }
      }
    }
  }
}

// ---------------- output projection (fp32 out) ----------------
// grid 128 = 8 xcd x 16 slots: mp = xcd + 8*(slot&3), np = slot>>2 (0..3).
__global__ __launch_bounds__(512, 2) void proj_out_kernel(
    const __bf16* __restrict__ Ob, const __bf16* __restrict__ wob,
    const float* __restrict__ bo, float* __restrict__ out) {
  __shared__ __align__(16) __bf16 Ab[2][256 * 64];
  __shared__ __align__(16) __bf16 Bb[2][256 * 64];

  const int lid = blockIdx.x;
  const int xcd = lid & 7, slot = lid >> 3;   // slot 0..15
  const int mp = xcd + 8 * (slot & 3);        // 0..31
  const int np = slot >> 2;                   // 0..3
  const int m0 = mp * 256, n0 = np * 256;

  floatx4 acc[8][4] = {};
  gemm256(Ob + (size_t)m0 * HH, wob + (size_t)n0 * HH, &Ab[0][0], &Bb[0][0], acc);

  const int t = threadIdx.x, lane = t & 63, quad = lane >> 4, l16 = lane & 15;
  const int wid = t >> 6, wm = (wid >> 2) * 128, wn = (wid & 3) * 64;
#pragma unroll
  for (int ni = 0; ni < 4; ++ni) {
    int n = n0 + wn + ni * 16 + l16;
    float bval = bo[n];
#pragma unroll
    for (int mi = 0; mi < 8; ++mi)
#pragma unroll
      for (int r = 0; r < 4; ++r) {
        int m = m0 + wm + mi * 16 + quad * 4 + r;
        out[(size_t)m * HH + n] = acc[mi][ni][r] + bval;
      }
  }
}

// ---------------- flash attention, shift-free softmax, XCD-swizzled -------
// flat grid 512: L = qt*64 + bh  =>  L&7 = bh&7 -> all 8 q-blocks of one
// (b,h) share an XCD; that (b,h)'s K/V (1MB) stays hot in its L2.
// R14 structure (proven): double-buffer, __syncthreads at loop top,
// prefetch distance 1, ones-column MFMA row-sums, z4 first-MFMA init,
// R8 in-register P transpose (cvt_pk + 2x permlane16_swap, sigma=(0,2,1,3)).
__global__ __launch_bounds__(256, 2) void attn_kernel(
    const __bf16* __restrict__ Q, const __bf16* __restrict__ Kc,
    const __bf16* __restrict__ Vt, __bf16* __restrict__ Ob) {
  __shared__ __align__(16) __bf16 Ks[2][64 * 64];
  __shared__ __align__(16) __bf16 Vs[2][64 * 64];

  const int t = threadIdx.x, lane = t & 63, quad = lane >> 4, l16 = lane & 15;
  const int wid = t >> 6;
  const int L = blockIdx.x;
  const int qt = L >> 6, bhx = L & 63;
  const int b = bhx >> 4, h = bhx & 15;
  const size_t bh = (size_t)b * NHH + h;
  const __bf16* Qg = Q + (bh * SS + (size_t)qt * 256) * DD;
  const __bf16* Kg = Kc + bh * SS * DD;
  const __bf16* Vg = Vt + bh * DD * SS;

  const int srow = t >> 3;  // 0..31
  const int sc = t & 7;

  const __bf16* KgA = Kg + (size_t)srow * DD + (sc ^ swz3(srow)) * 8;
  const __bf16* KgB = Kg + (size_t)(srow + 32) * DD + (sc ^ swz3(srow + 32)) * 8;
  const __bf16* VgA = Vg + (size_t)srow * SS + (sc ^ swz3(srow)) * 8;
  const __bf16* VgB = Vg + (size_t)(srow + 32) * SS + (sc ^ swz3(srow + 32)) * 8;

  bf16x8 qf[4][2];
#pragma unroll
  for (int ni = 0; ni < 4; ++ni)
#pragma unroll
    for (int ks = 0; ks < 2; ++ks)
      qf[ni][ks] = *(const bf16x8*)(Qg + (size_t)(wid * 64 + ni * 16 + l16) * DD
                                    + (ks * 4 + quad) * 8);

  floatx4 oacc[4][4] = {};
  floatx4 rsacc[4] = {};   // ones-column row sums: rsacc[mq][r] = rsum(q)
  const floatx4 z4 = {0.f, 0.f, 0.f, 0.f};
  bf16x8 ones;
#pragma unroll
  for (int i = 0; i < 8; ++i) ones[i] = (__bf16)1.0f;

  int koff[4][2];
#pragma unroll
  for (int mi = 0; mi < 4; ++mi) {
    int r = mi * 16 + l16;
#pragma unroll
    for (int ks = 0; ks < 2; ++ks)
      koff[mi][ks] = r * 64 + ((ks * 4 + quad) ^ swz3(r)) * 8;
  }
  const int sq = ((quad & 1) << 1) | (quad >> 1);  // 0->0 1->2 2->1 3->3
  int voff[4][2];
#pragma unroll
  for (int nj = 0; nj < 4; ++nj) {
    int r = nj * 16 + l16;
#pragma unroll
    for (int hf = 0; hf < 2; ++hf)
      voff[nj][hf] = r * 64 + ((hf * 4 + sq) ^ swz3(r)) * 8;
  }

  async16(KgA, &Ks[0][t * 8]);
  async16(KgB, &Ks[0][2048 + t * 8]);
  async16(VgA, &Vs[0][t * 8]);
  async16(VgB, &Vs[0][2048 + t * 8]);

  for (int kt = 0; kt < SS / 64; ++kt) {
    const int cur = kt & 1;
    __syncthreads();

    if (kt + 1 < SS / 64) {
      const int kk = (kt + 1) * 64;
      const int nxt = cur ^ 1;
      async16(KgA + (size_t)kk * DD, &Ks[nxt][t * 8]);
      async16(KgB + (size_t)kk * DD, &Ks[nxt][2048 + t * 8]);
      async16(VgA + kk, &Vs[nxt][t * 8]);
      async16(VgB + kk, &Vs[nxt][2048 + t * 8]);
    }

    // S^T = K Q^T : sacc[mi][ni] holds S^T[k = mi*16+quad*4+r][q = ni*16+l16]
    floatx4 sacc[4][4];
    {
      bf16x8 kf[4];
#pragma unroll
      for (int mi = 0; mi < 4; ++mi) kf[mi] = *(const bf16x8*)&Ks[cur][koff[mi][0]];
#pragma unroll
      for (int mi = 0; mi < 4; ++mi)
#pragma unroll
        for (int ni = 0; ni < 4; ++ni)
          sacc[mi][ni] = __builtin_amdgcn_mfma_f32_16x16x32_bf16(kf[mi], qf[ni][0],
                                                                 z4, 0, 0, 0);
#pragma unroll
      for (int mi = 0; mi < 4; ++mi) kf[mi] = *(const bf16x8*)&Ks[cur][koff[mi][1]];
#pragma unroll
      for (int mi = 0; mi < 4; ++mi)
#pragma unroll
        for (int ni = 0; ni < 4; ++ni)
          sacc[mi][ni] = __builtin_amdgcn_mfma_f32_16x16x32_bf16(kf[mi], qf[ni][1],
                                                                 sacc[mi][ni], 0, 0, 0);
    }

    // p = exp2(s); build PV A-frags in-register; rsum via ones-column MFMA.
#pragma unroll
    for (int hf = 0; hf < 2; ++hf) {
      bf16x8 ap[4], bv8[4];
#pragma unroll
      for (int mq = 0; mq < 4; ++mq) {
        float p[2][4];
#pragma unroll
        for (int m = 0; m < 2; ++m)
#pragma unroll
          for (int r = 0; r < 4; ++r)
            p[m][r] = __builtin_amdgcn_exp2f(sacc[hf * 2 + m][mq][r]);
        unsigned x0 = pkbf16(p[0][0], p[0][1]);
        unsigned x1 = pkbf16(p[0][2], p[0][3]);
        unsigned y0 = pkbf16(p[1][0], p[1][1]);
        unsigned y1 = pkbf16(p[1][2], p[1][3]);
        pswap16(x0, y0);
        pswap16(x1, y1);
        uintx4 u = {x0, x1, y0, y1};
        ap[mq] = __builtin_bit_cast(bf16x8, u);
      }
#pragma unroll
      for (int nj = 0; nj < 4; ++nj) bv8[nj] = *(const bf16x8*)&Vs[cur][voff[nj][hf]];
#pragma unroll
      for (int mq = 0; mq < 4; ++mq) {
#pragma unroll
        for (int nj = 0; nj < 4; ++nj)
          oacc[mq][nj] = __builtin_amdgcn_mfma_f32_16x16x32_bf16(ap[mq], bv8[nj],
                                                                 oacc[mq][nj], 0, 0, 0);
        rsacc[mq] = __builtin_amdgcn_mfma_f32_16x16x32_bf16(ap[mq], ones,
                                                            rsacc[mq], 0, 0, 0);
      }
    }
  }

  const int s0 = qt * 256 + wid * 64;
#pragma unroll
  for (int mq = 0; mq < 4; ++mq) {
#pragma unroll
    for (int r = 0; r < 4; ++r) {
      float inv = 1.f / rsacc[mq][r];   // row sum for q = mq*16+quad*4+r
      int s = s0 + mq * 16 + quad * 4 + r;
#pragma unroll
      for (int nj = 0; nj < 4; ++nj) {
        int d = nj * 16 + l16;
        Ob[((size_t)b * SS + s) * HH + h * DD + d] = (__bf16)(oacc[mq][nj][r] * inv);
      }
    }
  }
}

extern "C" void kernel_launch(void* const* d_in, const int* in_sizes, int n_in,
                              void* d_out, int out_size, void* d_ws, size_t ws_size,
                              hipStream_t stream) {
  const float* x  = (const float*)d_in[0];
  const float* Wq = (const float*)d_in[1];
  const float* bq = (const float*)d_in[2];
  const float* Wk = (const float*)d_in[3];
  const float* bk = (const float*)d_in[4];
  const float* Wv = (const float*)d_in[5];
  const float* bv = (const float*)d_in[6];
  const float* Wo = (const float*)d_in[7];
  const float* bo = (const float*)d_in[8];
  float* out = (float*)d_out;

  char* ws = (char*)d_ws;
  __bf16* xb  = (__bf16*)(ws);
  __bf16* wqb = (__bf16*)(ws + 16777216);
  __bf16* wkb = (__bf16*)(ws + 18874368);
  __bf16* wvb = (__bf16*)(ws + 20971520);
  __bf16* wob = (__bf16*)(ws + 23068672);
  __bf16* Qb  = (__bf16*)(ws + 25165824);
  __bf16* Kb  = (__bf16*)(ws + 41943040);
  __bf16* Vtb = (__bf16*)(ws + 58720256);
  __bf16* Ob  = (__bf16*)(ws + 75497472);

  cast_bf16_kernel<<<dim3(256, 1, 5), 256, 0, stream>>>(x, Wq, Wk, Wv, Wo,
                                                        xb, wqb, wkb, wvb, wob);
  proj_qkv_kernel<<<dim3(384), 512, 0, stream>>>(xb, wqb, wkb, wvb,
                                                 bq, bk, bv, Qb, Kb, Vtb);
  attn_kernel<<<dim3(512), 256, 0, stream>>>(Qb, Kb, Vtb, Ob);
  proj_out_kernel<<<dim3(128), 512, 0, stream>>>(Ob, wob, bo, out);
}

// Round 10
// 269.140 us; speedup vs baseline: 1.0787x; 1.0787x over previous
//
#include <hip/hip_runtime.h>

// MHA forward, bf16 MFMA everywhere. B=4 S=2048 H=1024 NH=16 D=64.
// R17: R16's 256-tile reverted (grid 384 = 1.5 rounds -> half-empty 2nd
// round; WRITE doubled). Back to R14's 128x256 tile + proven sync chain,
// ONE change: BK 64->32 => LDS 24KB/buffer x3 = 72KB => 2 blocks/CU
// (4 waves/SIMD). Co-resident blocks cover each other's barrier-drain
// stalls (the lever that worked for attn; R14 proj was 1 block/CU with
// ~50% stall). Per kt: {8 ds_read_b128; 3 stage async16; barrier;
// lgkm(0); 16 MFMA; vmcnt(3 = own per-kt loads); barrier}; prefetch
// distance 2; full vmcnt(0) prologue drain (R13 rule). Read/stage layout
// = R6-R8's proven swz2 BK=32 pattern. attn = R14 (proven), cast same.

#define DEV __device__ __forceinline__

typedef __bf16 bf16x8 __attribute__((ext_vector_type(8)));
typedef __bf16 bf16x4 __attribute__((ext_vector_type(4)));
typedef __bf16 bf16x2 __attribute__((ext_vector_type(2)));
typedef float floatx4 __attribute__((ext_vector_type(4)));
typedef unsigned int uintx4 __attribute__((ext_vector_type(4)));

constexpr int Bdim = 4, SS = 2048, HH = 1024, NHH = 16, DD = 64;
constexpr int MM = Bdim * SS;  // 8192

DEV void async16(const void* g, void* l) {
  __builtin_amdgcn_global_load_lds(
      (const __attribute__((address_space(1))) unsigned int*)g,
      (__attribute__((address_space(3))) unsigned int*)l, 16, 0, 0);
}

DEV int swz2(int r) { return (r ^ (r >> 2)) & 3; }   // 4-chunk rows (32 cols)
DEV int swz3(int r) { return (r ^ (r >> 3)) & 7; }   // 8-chunk rows (64 cols)

// pack two f32 -> one dword of 2 bf16 (compiler emits v_cvt_pk_bf16_f32)
DEV unsigned pkbf16(float lo, float hi) {
  bf16x2 t;
  t[0] = (__bf16)lo;
  t[1] = (__bf16)hi;
  return __builtin_bit_cast(unsigned, t);
}

// v_permlane16_swap_b32: a.row{1,3} <-> b.row{0,2} (rows = 16-lane groups).
DEV void pswap16(unsigned& a, unsigned& b) {
  asm("v_permlane16_swap_b32 %0, %1" : "+v"(a), "+v"(b));
}

// ---------------- cast fp32 -> bf16 ----------------
__global__ __launch_bounds__(256) void cast_bf16_kernel(
    const float* __restrict__ x, const float* __restrict__ wq,
    const float* __restrict__ wk, const float* __restrict__ wv,
    const float* __restrict__ wo,
    __bf16* __restrict__ xb, __bf16* __restrict__ wqb, __bf16* __restrict__ wkb,
    __bf16* __restrict__ wvb, __bf16* __restrict__ wob) {
  const float* src; __bf16* dst; int n4;
  switch (blockIdx.z) {
    case 0: src = x;  dst = xb;  n4 = MM * HH / 4; break;
    case 1: src = wq; dst = wqb; n4 = HH * HH / 4; break;
    case 2: src = wk; dst = wkb; n4 = HH * HH / 4; break;
    case 3: src = wv; dst = wvb; n4 = HH * HH / 4; break;
    default: src = wo; dst = wob; n4 = HH * HH / 4; break;
  }
  int stride = gridDim.x * blockDim.x;
  for (int i = blockIdx.x * blockDim.x + threadIdx.x; i < n4; i += stride) {
    float4 v = ((const float4*)src)[i];
    bf16x4 o;
    o[0] = (__bf16)v.x; o[1] = (__bf16)v.y; o[2] = (__bf16)v.z; o[3] = (__bf16)v.w;
    ((bf16x4*)dst)[i] = o;
  }
}

// ---- 128x256 GEMM core, K=1024, BK=32 single-phase, 3-buf, 2 blk/CU ----
// 512 thr = 8 waves (2M x 4N), per-wave 64x64 (acc[4][4]). LDS: A[128][32]
// (8KB) + B[256][32] (16KB) per buffer, 3 buffers = 72KB. 3 async16 per
// thread per kt. Bottom vmcnt(3) = own loads issued this kt (tile kt+2)
// stay in flight; tile kt+1's (issued kt-1) forced-retired.
DEV void gemm32(const __bf16* __restrict__ Ablk, const __bf16* __restrict__ Bblk,
                __bf16* Ab, __bf16* Bb, floatx4 acc[4][4]) {
  const int t = threadIdx.x;
  const int lane = t & 63, quad = lane >> 4, l16 = lane & 15;
  const int wid = t >> 6;
  const int wm = (wid >> 2) * 64, wn = (wid & 3) * 64;

  const int srow = t >> 2, sc = t & 3;   // srow 0..127
  const __bf16* Ag  = Ablk + (size_t)srow * HH + (sc ^ swz2(srow)) * 8;
  const __bf16* Bg0 = Bblk + (size_t)srow * HH + (sc ^ swz2(srow)) * 8;
  const __bf16* Bg1 = Bblk + (size_t)(srow + 128) * HH + (sc ^ swz2(srow + 128)) * 8;

  int aoff[4], boff[4];
#pragma unroll
  for (int i = 0; i < 4; ++i) {
    int ra = wm + i * 16 + l16;
    aoff[i] = ra * 32 + (quad ^ swz2(ra)) * 8;
    int rb = wn + i * 16 + l16;
    boff[i] = rb * 32 + (quad ^ swz2(rb)) * 8;
  }

  // prologue: stage K-tiles 0 and 1 (6 loads); FULL drain (order-robust).
#pragma unroll
  for (int tile = 0; tile < 2; ++tile) {
    const int ks = tile * 32;
    async16(Ag + ks,  Ab + tile * 4096 + t * 8);
    async16(Bg0 + ks, Bb + tile * 8192 + t * 8);
    async16(Bg1 + ks, Bb + tile * 8192 + 4096 + t * 8);
  }
  asm volatile("s_waitcnt vmcnt(0)" ::: "memory");
  __builtin_amdgcn_s_barrier();

  int cb = 0, sb = 2;
#pragma unroll 1
  for (int kt = 0; kt < 32; ++kt) {
    const __bf16* Ac = Ab + cb * 4096;
    const __bf16* Bc = Bb + cb * 8192;
    __bf16* Asg = Ab + sb * 4096;
    __bf16* Bsg = Bb + sb * 8192;
    const int ks = (kt + 2) * 32;
    const bool st = kt + 2 < 32;

    bf16x8 af[4], bfr[4];
#pragma unroll
    for (int i = 0; i < 4; ++i) af[i] = *(const bf16x8*)&Ac[aoff[i]];
#pragma unroll
    for (int i = 0; i < 4; ++i) bfr[i] = *(const bf16x8*)&Bc[boff[i]];
    if (st) {
      async16(Ag + ks,  Asg + t * 8);
      async16(Bg0 + ks, Bsg + t * 8);
      async16(Bg1 + ks, Bsg + 4096 + t * 8);
    }
    asm volatile("" ::: "memory");
    __builtin_amdgcn_s_barrier();
    asm volatile("s_waitcnt lgkmcnt(0)" ::: "memory");
    __builtin_amdgcn_sched_barrier(0);
    __builtin_amdgcn_s_setprio(1);
#pragma unroll
    for (int mi = 0; mi < 4; ++mi)
#pragma unroll
      for (int ni = 0; ni < 4; ++ni)
        acc[mi][ni] = __builtin_amdgcn_mfma_f32_16x16x32_bf16(af[mi], bfr[ni],
                                                              acc[mi][ni], 0, 0, 0);
    __builtin_amdgcn_s_setprio(0);
    // bottom: tile kt+1 (issued kt-1) landed; keep this kt's 3 in flight.
    if (st) asm volatile("s_waitcnt vmcnt(3)" ::: "memory");
    else    asm volatile("s_waitcnt vmcnt(0)" ::: "memory");
    asm volatile("" ::: "memory");
    __builtin_amdgcn_s_barrier();

    cb = cb == 2 ? 0 : cb + 1;
    sb = sb == 2 ? 0 : sb + 1;
  }
}

// ---------------- QKV projection: one mode per block ----------------
// grid 768 = 8 xcd x 96 slots: mp = xcd + 8*(slot&7) (x panels stay L2-hot
// per XCD across all nt rounds), nt = slot>>3 in 0..11, mode = nt>>2.
__global__ __launch_bounds__(512, 4) void proj_qkv_kernel(
    const __bf16* __restrict__ xb,
    const __bf16* __restrict__ wqb, const __bf16* __restrict__ wkb,
    const __bf16* __restrict__ wvb,
    const float* __restrict__ bq, const float* __restrict__ bk,
    const float* __restrict__ bv,
    __bf16* __restrict__ Q, __bf16* __restrict__ Kc, __bf16* __restrict__ Vt) {
  __shared__ __align__(16) __bf16 Ab[3][128 * 32];
  __shared__ __align__(16) __bf16 Bb[3][256 * 32];

  const int lid = blockIdx.x;
  const int xcd = lid & 7, slot = lid >> 3;   // slot 0..95
  const int mp = xcd + 8 * (slot & 7);        // 0..63
  const int nt = slot >> 3;                   // 0..11
  const int mode = nt >> 2;
  const int n0 = (nt & 3) * 256;
  const int m0 = mp * 128;

  const __bf16* W = mode == 0 ? wqb : mode == 1 ? wkb : wvb;
  const float* bias = mode == 0 ? bq : mode == 1 ? bk : bv;

  floatx4 acc[4][4] = {};
  gemm32(xb + (size_t)m0 * HH, W + (size_t)n0 * HH, &Ab[0][0], &Bb[0][0], acc);

  const int t = threadIdx.x, lane = t & 63, quad = lane >> 4, l16 = lane & 15;
  const int wid = t >> 6, wm = (wid >> 2) * 64, wn = (wid & 3) * 64;
  const float qscale = 0.125f * 1.44269504088896f;  // 1/sqrt(D) * log2(e)

#pragma unroll
  for (int ni = 0; ni < 4; ++ni) {
    int n = n0 + wn + ni * 16 + l16;   // 0..1023 within mode
    float bval = bias[n];
    int h = n >> 6, d = n & 63;
#pragma unroll
    for (int mi = 0; mi < 4; ++mi) {
      int mbase = m0 + wm + mi * 16 + quad * 4;
      int bb = mbase >> 11, sbase = mbase & (SS - 1);
      size_t bh = (size_t)(bb * NHH + h);
      if (mode == 2) {
        bf16x4 pv;
#pragma unroll
        for (int r = 0; r < 4; ++r) pv[r] = (__bf16)(acc[mi][ni][r] + bval);
        *(bf16x4*)&Vt[(bh * DD + d) * SS + sbase] = pv;
      } else {
#pragma unroll
        for (int r = 0; r < 4; ++r) {
          float v = acc[mi][ni][r] + bval;
          if (mode == 0) Q [(bh * SS + sbase + r) * DD + d] = (__bf16)(v * qscale);
          else           Kc[(bh * SS + sbase + r) * DD + d] = (__bf16)v;
        }
      }
    }
  }
}

// ---------------- output projection (fp32 out) ----------------
// grid 256 = 8 xcd x 32 slots: mp = xcd + 8*(slot&7), np = slot>>3 in 0..3.
__global__ __launch_bounds__(512, 4) void proj_out_kernel(
    const __bf16* __restrict__ Ob, const __bf16* __restrict__ wob,
    const float* __restrict__ bo, float* __restrict__ out) {
  __shared__ __align__(16) __bf16 Ab[3][128 * 32];
  __shared__ __align__(16) __bf16 Bb[3][256 * 32];

  const int lid = blockIdx.x;
  const int xcd = lid & 7, slot = lid >> 3;   // slot 0..31
  const int mp = xcd + 8 * (slot & 7);        // 0..63
  const int np = slot >> 3;                   // 0..3
  const int m0 = mp * 128, n0 = np * 256;

  floatx4 acc[4][4] = {};
  gemm32(Ob + (size_t)m0 * HH, wob + (size_t)n0 * HH, &Ab[0][0], &Bb[0][0], acc);

  const int t = threadIdx.x, lane = t & 63, quad = lane >> 4, l16 = lane & 15;
  const int wid = t >> 6, wm = (wid >> 2) * 64, wn = (wid & 3) * 64;
#pragma unroll
  for (int ni = 0; ni < 4; ++ni) {
    int n = n0 + wn + ni * 16 + l16;
    float bval = bo[n];
#pragma unroll
    for (int mi = 0; mi < 4; ++mi)
#pragma unroll
      for (int r = 0; r < 4; ++r) {
        int m = m0 + wm + mi * 16 + quad * 4 + r;
        out[(size_t)m * HH + n] = acc[mi][ni][r] + bval;
      }
  }
}

// ---------------- flash attention, shift-free softmax, XCD-swizzled -------
// flat grid 512: L = qt*64 + bh  =>  L&7 = bh&7 -> all 8 q-blocks of one
// (b,h) share an XCD; that (b,h)'s K/V (1MB) stays hot in its L2.
// R14 structure (proven): double-buffer, __syncthreads at loop top,
// prefetch distance 1, ones-column MFMA row-sums, z4 first-MFMA init,
// R8 in-register P transpose (cvt_pk + 2x permlane16_swap, sigma=(0,2,1,3)).
__global__ __launch_bounds__(256, 2) void attn_kernel(
    const __bf16* __restrict__ Q, const __bf16* __restrict__ Kc,
    const __bf16* __restrict__ Vt, __bf16* __restrict__ Ob) {
  __shared__ __align__(16) __bf16 Ks[2][64 * 64];
  __shared__ __align__(16) __bf16 Vs[2][64 * 64];

  const int t = threadIdx.x, lane = t & 63, quad = lane >> 4, l16 = lane & 15;
  const int wid = t >> 6;
  const int L = blockIdx.x;
  const int qt = L >> 6, bhx = L & 63;
  const int b = bhx >> 4, h = bhx & 15;
  const size_t bh = (size_t)b * NHH + h;
  const __bf16* Qg = Q + (bh * SS + (size_t)qt * 256) * DD;
  const __bf16* Kg = Kc + bh * SS * DD;
  const __bf16* Vg = Vt + bh * DD * SS;

  const int srow = t >> 3;  // 0..31
  const int sc = t & 7;

  const __bf16* KgA = Kg + (size_t)srow * DD + (sc ^ swz3(srow)) * 8;
  const __bf16* KgB = Kg + (size_t)(srow + 32) * DD + (sc ^ swz3(srow + 32)) * 8;
  const __bf16* VgA = Vg + (size_t)srow * SS + (sc ^ swz3(srow)) * 8;
  const __bf16* VgB = Vg + (size_t)(srow + 32) * SS + (sc ^ swz3(srow + 32)) * 8;

  bf16x8 qf[4][2];
#pragma unroll
  for (int ni = 0; ni < 4; ++ni)
#pragma unroll
    for (int ks = 0; ks < 2; ++ks)
      qf[ni][ks] = *(const bf16x8*)(Qg + (size_t)(wid * 64 + ni * 16 + l16) * DD
                                    + (ks * 4 + quad) * 8);

  floatx4 oacc[4][4] = {};
  floatx4 rsacc[4] = {};   // ones-column row sums: rsacc[mq][r] = rsum(q)
  const floatx4 z4 = {0.f, 0.f, 0.f, 0.f};
  bf16x8 ones;
#pragma unroll
  for (int i = 0; i < 8; ++i) ones[i] = (__bf16)1.0f;

  int koff[4][2];
#pragma unroll
  for (int mi = 0; mi < 4; ++mi) {
    int r = mi * 16 + l16;
#pragma unroll
    for (int ks = 0; ks < 2; ++ks)
      koff[mi][ks] = r * 64 + ((ks * 4 + quad) ^ swz3(r)) * 8;
  }
  const int sq = ((quad & 1) << 1) | (quad >> 1);  // 0->0 1->2 2->1 3->3
  int voff[4][2];
#pragma unroll
  for (int nj = 0; nj < 4; ++nj) {
    int r = nj * 16 + l16;
#pragma unroll
    for (int hf = 0; hf < 2; ++hf)
      voff[nj][hf] = r * 64 + ((hf * 4 + sq) ^ swz3(r)) * 8;
  }

  async16(KgA, &Ks[0][t * 8]);
  async16(KgB, &Ks[0][2048 + t * 8]);
  async16(VgA, &Vs[0][t * 8]);
  async16(VgB, &Vs[0][2048 + t * 8]);

  for (int kt = 0; kt < SS / 64; ++kt) {
    const int cur = kt & 1;
    __syncthreads();

    if (kt + 1 < SS / 64) {
      const int kk = (kt + 1) * 64;
      const int nxt = cur ^ 1;
      async16(KgA + (size_t)kk * DD, &Ks[nxt][t * 8]);
      async16(KgB + (size_t)kk * DD, &Ks[nxt][2048 + t * 8]);
      async16(VgA + kk, &Vs[nxt][t * 8]);
      async16(VgB + kk, &Vs[nxt][2048 + t * 8]);
    }

    // S^T = K Q^T : sacc[mi][ni] holds S^T[k = mi*16+quad*4+r][q = ni*16+l16]
    floatx4 sacc[4][4];
    {
      bf16x8 kf[4];
#pragma unroll
      for (int mi = 0; mi < 4; ++mi) kf[mi] = *(const bf16x8*)&Ks[cur][koff[mi][0]];
#pragma unroll
      for (int mi = 0; mi < 4; ++mi)
#pragma unroll
        for (int ni = 0; ni < 4; ++ni)
          sacc[mi][ni] = __builtin_amdgcn_mfma_f32_16x16x32_bf16(kf[mi], qf[ni][0],
                                                                 z4, 0, 0, 0);
#pragma unroll
      for (int mi = 0; mi < 4; ++mi) kf[mi] = *(const bf16x8*)&Ks[cur][koff[mi][1]];
#pragma unroll
      for (int mi = 0; mi < 4; ++mi)
#pragma unroll
        for (int ni = 0; ni < 4; ++ni)
          sacc[mi][ni] = __builtin_amdgcn_mfma_f32_16x16x32_bf16(kf[mi], qf[ni][1],
                                                                 sacc[mi][ni], 0, 0, 0);
    }

    // p = exp2(s); build PV A-frags in-register; rsum via ones-column MFMA.
#pragma unroll
    for (int hf = 0; hf < 2; ++hf) {
      bf16x8 ap[4], bv8[4];
#pragma unroll
      for (int mq = 0; mq < 4; ++mq) {
        float p[2][4];
#pragma unroll
        for (int m = 0; m < 2; ++m)
#pragma unroll
          for (int r = 0; r < 4; ++r)
            p[m][r] = __builtin_amdgcn_exp2f(sacc[hf * 2 + m][mq][r]);
        unsigned x0 = pkbf16(p[0][0], p[0][1]);
        unsigned x1 = pkbf16(p[0][2], p[0][3]);
        unsigned y0 = pkbf16(p[1][0], p[1][1]);
        unsigned y1 = pkbf16(p[1][2], p[1][3]);
        pswap16(x0, y0);
        pswap16(x1, y1);
        uintx4 u = {x0, x1, y0, y1};
        ap[mq] = __builtin_bit_cast(bf16x8, u);
      }
#pragma unroll
      for (int nj = 0; nj < 4; ++nj) bv8[nj] = *(const bf16x8*)&Vs[cur][voff[nj][hf]];
#pragma unroll
      for (int mq = 0; mq < 4; ++mq) {
#pragma unroll
        for (int nj = 0; nj < 4; ++nj)
          oacc[mq][nj] = __builtin_amdgcn_mfma_f32_16x16x32_bf16(ap[mq], bv8[nj],
                                                                 oacc[mq][nj], 0, 0, 0);
        rsacc[mq] = __builtin_amdgcn_mfma_f32_16x16x32_bf16(ap[mq], ones,
                                                            rsacc[mq], 0, 0, 0);
      }
    }
  }

  const int s0 = qt * 256 + wid * 64;
#pragma unroll
  for (int mq = 0; mq < 4; ++mq) {
#pragma unroll
    for (int r = 0; r < 4; ++r) {
      float inv = 1.f / rsacc[mq][r];   // row sum for q = mq*16+quad*4+r
      int s = s0 + mq * 16 + quad * 4 + r;
#pragma unroll
      for (int nj = 0; nj < 4; ++nj) {
        int d = nj * 16 + l16;
        Ob[((size_t)b * SS + s) * HH + h * DD + d] = (__bf16)(oacc[mq][nj][r] * inv);
      }
    }
  }
}

extern "C" void kernel_launch(void* const* d_in, const int* in_sizes, int n_in,
                              void* d_out, int out_size, void* d_ws, size_t ws_size,
                              hipStream_t stream) {
  const float* x  = (const float*)d_in[0];
  const float* Wq = (const float*)d_in[1];
  const float* bq = (const float*)d_in[2];
  const float* Wk = (const float*)d_in[3];
  const float* bk = (const float*)d_in[4];
  const float* Wv = (const float*)d_in[5];
  const float* bv = (const float*)d_in[6];
  const float* Wo = (const float*)d_in[7];
  const float* bo = (const float*)d_in[8];
  float* out = (float*)d_out;

  char* ws = (char*)d_ws;
  __bf16* xb  = (__bf16*)(ws);
  __bf16* wqb = (__bf16*)(ws + 16777216);
  __bf16* wkb = (__bf16*)(ws + 18874368);
  __bf16* wvb = (__bf16*)(ws + 20971520);
  __bf16* wob = (__bf16*)(ws + 23068672);
  __bf16* Qb  = (__bf16*)(ws + 25165824);
  __bf16* Kb  = (__bf16*)(ws + 41943040);
  __bf16* Vtb = (__bf16*)(ws + 58720256);
  __bf16* Ob  = (__bf16*)(ws + 75497472);

  cast_bf16_kernel<<<dim3(256, 1, 5), 256, 0, stream>>>(x, Wq, Wk, Wv, Wo,
                                                        xb, wqb, wkb, wvb, wob);
  proj_qkv_kernel<<<dim3(768), 512, 0, stream>>>(xb, wqb, wkb, wvb,
                                                 bq, bk, bv, Qb, Kb, Vtb);
  attn_kernel<<<dim3(512), 256, 0, stream>>>(Qb, Kb, Vtb, Ob);
  proj_out_kernel<<<dim3(256), 512, 0, stream>>>(Ob, wob, bo, out);
}